// Round 2
// baseline (381.233 us; speedup 1.0000x reference)
//
#include <hip/hip_runtime.h>

// Problem constants (from reference)
#define Bc 4
#define Nc 16384
#define Hc 8
#define Dc 128
#define Kc 32
#define STRIDEc 16
#define Mc 1023   // (N-K)/STRIDE + 1
#define Tm 8      // windows per block

// Block = (b, m-tile of Tm windows). 256 threads = 8 h * 32 float4-lanes over D.
// Each thread streams 16*Tm+16 input rows; each row r = 16*i + t contributes to
// window i (weight w[t]) and window i-1 (weight w[16+t]). Overlap between
// adjacent windows is reused in registers -> read amplification 144/128 = 1.125x.
__global__ __launch_bounds__(256) void compress_kv_kernel(
    const float* __restrict__ x,
    const float* __restrict__ w,
    const float* __restrict__ pe,
    float* __restrict__ out)
{
    __shared__ float s_w[Kc];
    __shared__ __align__(16) float s_bias[Dc];

    const int tid = threadIdx.x;

    // Weights pre-divided by K.
    if (tid < Kc) s_w[tid] = w[tid] * (1.0f / (float)Kc);
    __syncthreads();

    // bias[d] = sum_k pe[k,d] * w[k]/K  (pe is 16 KB -> L2-resident)
    if (tid < Dc) {
        float bsum = 0.0f;
        #pragma unroll
        for (int k = 0; k < Kc; ++k) bsum += pe[k * Dc + tid] * s_w[k];
        s_bias[tid] = bsum;
    }
    __syncthreads();

    const int NT  = (Mc + Tm - 1) / Tm;       // 128 tiles per b
    const int b   = blockIdx.x / NT;
    const int m0  = (blockIdx.x % NT) * Tm;
    const int n0  = m0 * STRIDEc;
    const int d4  = tid & 31;                 // float4 lane over D
    const int h   = tid >> 5;                 // 0..7

    const float4* __restrict__ x4 = (const float4*)x;
    const int step = Hc * (Dc / 4);           // one n-row in float4 units (256)
    const int base = ((b * Nc + n0) * Hc + h) * (Dc / 4) + d4;

    const float4 bias = ((const float4*)s_bias)[d4];
    float4 acc[Tm];
    #pragma unroll
    for (int j = 0; j < Tm; ++j) acc[j] = bias;

    const int windows = (Mc - m0 < Tm) ? (Mc - m0) : Tm;

    if (windows == Tm && n0 + 16 * Tm + 16 <= Nc) {
        // Fast path: full tile, all rows in range.
        #pragma unroll
        for (int i = 0; i <= Tm; ++i) {
            #pragma unroll
            for (int t = 0; t < 16; ++t) {
                const float4 xv = x4[base + (16 * i + t) * step];
                if (i < Tm) {
                    const float wk = s_w[t];
                    acc[i].x += xv.x * wk; acc[i].y += xv.y * wk;
                    acc[i].z += xv.z * wk; acc[i].w += xv.w * wk;
                }
                if (i >= 1) {
                    const float wk = s_w[16 + t];
                    acc[i-1].x += xv.x * wk; acc[i-1].y += xv.y * wk;
                    acc[i-1].z += xv.z * wk; acc[i-1].w += xv.w * wk;
                }
            }
        }
    } else {
        // Tail tile (m0 = 1016: 7 windows, 128 rows).
        const int rows = (Nc - n0 < 16 * Tm + 16) ? (Nc - n0) : (16 * Tm + 16);
        #pragma unroll
        for (int i = 0; i <= Tm; ++i) {
            #pragma unroll
            for (int t = 0; t < 16; ++t) {
                const int r = 16 * i + t;
                if (r < rows) {
                    const float4 xv = x4[base + r * step];
                    if (i < windows) {
                        const float wk = s_w[t];
                        acc[i].x += xv.x * wk; acc[i].y += xv.y * wk;
                        acc[i].z += xv.z * wk; acc[i].w += xv.w * wk;
                    }
                    if (i >= 1 && (i - 1) < windows) {
                        const float wk = s_w[16 + t];
                        acc[i-1].x += xv.x * wk; acc[i-1].y += xv.y * wk;
                        acc[i-1].z += xv.z * wk; acc[i-1].w += xv.w * wk;
                    }
                }
            }
        }
    }

    float4* __restrict__ out4 = (float4*)out;
    #pragma unroll
    for (int j = 0; j < Tm; ++j) {
        if (j < windows) {
            const int obase = ((b * Mc + (m0 + j)) * Hc + h) * (Dc / 4) + d4;
            out4[obase] = acc[j];
        }
    }
}

extern "C" void kernel_launch(void* const* d_in, const int* in_sizes, int n_in,
                              void* d_out, int out_size, void* d_ws, size_t ws_size,
                              hipStream_t stream) {
    const float* x  = (const float*)d_in[0];
    const float* w  = (const float*)d_in[1];
    const float* pe = (const float*)d_in[2];
    float* out = (float*)d_out;

    const int NT = (Mc + Tm - 1) / Tm;      // 128
    const int grid = Bc * NT;               // 512 blocks
    compress_kv_kernel<<<grid, 256, 0, stream>>>(x, w, pe, out);
}